// Round 19
// baseline (371.948 us; speedup 1.0000x reference)
//
#include <hip/hip_runtime.h>

#define BLK 256
#define BLK2 1024            // wide blocks for level-1 hist/scatter
#define BSHIFT 8
#define BSIZE 256            // nodes per dst bucket == level-2 bins
#define NSLICE 256           // edge slices for level-1 (long runs -> low write amp)
#define SCAN_T 1024          // k_base scan width (K <= 1024)
#define KPAD 1024            // level-1 bin array size (K <= 1024)
#define EPT 8                // edges per thread per tile
#define TILE2 (BLK2 * EPT)   // level-1 staging tile (8192)
#define S2BLK 1024           // k_sort2 block size
#define S2CAP 18432          // max edges per bucket staged in LDS (72 KB)
#define S2MAXJ 18            // S2CAP / S2BLK

typedef int iv4 __attribute__((ext_vector_type(4)));

template <typename T>
__device__ __forceinline__ T ntload(const T* p) { return __builtin_nontemporal_load(p); }

__device__ __forceinline__ iv4 ntload4(const int* p) {
    return __builtin_nontemporal_load((const iv4*)p);
}

// DPP wave-sum (rocPRIM gfx9 sequence): result lands in lane 63.
template <int CTRL>
__device__ __forceinline__ float dpp_add(float v) {
    int t = __builtin_amdgcn_update_dpp(0, __float_as_int(v), CTRL, 0xf, 0xf, true);
    return v + __int_as_float(t);
}
__device__ __forceinline__ float wave_sum63(float v) {
    v = dpp_add<0x111>(v);   // row_shr:1
    v = dpp_add<0x112>(v);   // row_shr:2
    v = dpp_add<0x114>(v);   // row_shr:4
    v = dpp_add<0x118>(v);   // row_shr:8
    v = dpp_add<0x142>(v);   // row_bcast:15
    v = dpp_add<0x143>(v);   // row_bcast:31 -> lane63 = total
    return v;
}

// ---------------- level-1: bucket by dst>>8 (no global atomics) -------------

__global__ void __launch_bounds__(BLK2) k_hist(const int* __restrict__ dst,
                                               int* __restrict__ partial,
                                               int E, int chunk, int K) {
    extern __shared__ int cnt[];
    int s = blockIdx.x;
    for (int i = threadIdx.x; i < K; i += BLK2) cnt[i] = 0;
    __syncthreads();
    int lo = s * chunk, hi = min(E, lo + chunk);
    int a0 = min((lo + 3) & ~3, hi);
    int a1 = max(hi & ~3, a0);
    for (int i = lo + threadIdx.x; i < a0; i += BLK2)
        atomicAdd(&cnt[((unsigned)ntload(dst + i)) >> BSHIFT], 1);
    for (int i = a0 + 4 * threadIdx.x; i < a1; i += 4 * BLK2) {
        iv4 q = ntload4(dst + i);
        atomicAdd(&cnt[((unsigned)q.x) >> BSHIFT], 1);
        atomicAdd(&cnt[((unsigned)q.y) >> BSHIFT], 1);
        atomicAdd(&cnt[((unsigned)q.z) >> BSHIFT], 1);
        atomicAdd(&cnt[((unsigned)q.w) >> BSHIFT], 1);
    }
    for (int i = a1 + threadIdx.x; i < hi; i += BLK2)
        atomicAdd(&cnt[((unsigned)ntload(dst + i)) >> BSHIFT], 1);
    __syncthreads();
    int* prow = partial + (size_t)s * K;
    for (int i = threadIdx.x; i < K; i += BLK2) prow[i] = cnt[i];
}

__global__ void __launch_bounds__(NSLICE) k_colscan(int* __restrict__ partial,
                                                    int* __restrict__ totals, int K) {
    __shared__ int sh[NSLICE];
    int k = blockIdx.x;
    int t = threadIdx.x;                  // blockDim.x == NSLICE
    int v = partial[(size_t)t * K + k];
    sh[t] = v;
    __syncthreads();
    for (int off = 1; off < NSLICE; off <<= 1) {
        int u = (t >= off) ? sh[t - off] : 0;
        __syncthreads();
        sh[t] += u;
        __syncthreads();
    }
    partial[(size_t)t * K + k] = sh[t] - v;
    if (t == NSLICE - 1) totals[k] = sh[t];
}

__global__ void __launch_bounds__(SCAN_T) k_base(const int* __restrict__ totals,
                                                 int* __restrict__ base, int K) {
    __shared__ int sh[SCAN_T];
    int t = threadIdx.x;
    int v = (t < K) ? totals[t] : 0;
    sh[t] = v;
    __syncthreads();
    for (int off = 1; off < SCAN_T; off <<= 1) {
        int u = (t >= off) ? sh[t - off] : 0;
        __syncthreads();
        sh[t] += u;
        __syncthreads();
    }
    if (t < K) base[t + 1] = sh[t];
    if (t == 0) base[0] = 0;
}

// 1024-thread tile counting-sort scatter with per-bucket LDS residual
// write-combining: every global line written once (full) except run-boundary
// heads. packed = (dst_local << sbits) | src
__global__ void __launch_bounds__(BLK2) k_scatter(const int* __restrict__ src,
                                                  const int* __restrict__ dst,
                                                  const int* __restrict__ offs,
                                                  const int* __restrict__ base,
                                                  int* __restrict__ packed,
                                                  int E, int chunk, int K, int sbits) {
    __shared__ int cnt[KPAD];
    __shared__ int tsum[KPAD];
    __shared__ int gstart[KPAD];
    __shared__ int fesh[KPAD];
    __shared__ int cur[KPAD];
    __shared__ int res[KPAD];
    __shared__ int sval[TILE2];
    __shared__ int sadr[TILE2];
    extern __shared__ int resbuf[];       // K * 16 ints (partial-line images)
    int s = blockIdx.x;
    int tid = threadIdx.x;
    const int* orow = offs + (size_t)s * K;
    cur[tid] = (tid < K) ? orow[tid] + base[tid] : 0;
    res[tid] = 0;
    int lo = s * chunk, hi = min(E, lo + chunk);

    for (int tlo = lo; tlo < hi; tlo += TILE2) {
        cnt[tid] = 0;
        __syncthreads();

        int kk[EPT], rr[EPT], vv[EPT];
#pragma unroll
        for (int j = 0; j < EPT; ++j) {
            int i = tlo + j * BLK2 + tid;
            kk[j] = -1;
            if (i < hi) {
                int d = ntload(dst + i);
                int sc = ntload(src + i);
                kk[j] = ((unsigned)d) >> BSHIFT;
                vv[j] = ((d & (BSIZE - 1)) << sbits) | sc;
                rr[j] = atomicAdd(&cnt[kk[j]], 1);
            }
        }
        __syncthreads();

        // 1024-wide bin scan (staging base)
        int c = cnt[tid];
        tsum[tid] = c;
        __syncthreads();
        for (int off = 1; off < KPAD; off <<= 1) {
            int u = (tid >= off) ? tsum[tid - off] : 0;
            __syncthreads();
            tsum[tid] += u;
            __syncthreads();
        }
        // bucket-owner bookkeeping: flush window + old-residual line completion
        if (tid < K) {
            int cur_old = cur[tid];
            int res_old = res[tid];
            int ds = cur_old - res_old;
            int fe = (cur_old + c) & ~15;
            int flushHi = min(fe, cur_old);
            for (int p = ds; p < flushHi; ++p)
                packed[p] = resbuf[tid * 16 + (p & 15)];
            res[tid] = (cur_old + c) - max(fe, ds);
            cur[tid] = cur_old + c;
            fesh[tid] = fe;
            gstart[tid] = cur_old;
        }
        cnt[tid] = tsum[tid] - c;         // exclusive staging base
        __syncthreads();

        // stage bucket-ordered; tail (pos >= fe) goes to residual buffer
#pragma unroll
        for (int j = 0; j < EPT; ++j) {
            if (kk[j] >= 0) {
                int idx = cnt[kk[j]] + rr[j];
                int pos = gstart[kk[j]] + rr[j];
                sval[idx] = vv[j];
                if (pos < fesh[kk[j]]) {
                    sadr[idx] = pos;
                } else {
                    sadr[idx] = -1;
                    resbuf[kk[j] * 16 + (pos & 15)] = vv[j];
                }
            }
        }
        __syncthreads();

        // coalesced burst flush of line-complete portion
        int tot = min(hi - tlo, TILE2);
        for (int i2 = tid; i2 < tot; i2 += BLK2) {
            int a2 = sadr[i2];
            if (a2 >= 0) packed[a2] = sval[i2];
        }
        __syncthreads();
    }

    // final residual flush (run tails; boundary lines shared with next run)
    if (tid < K) {
        int cu = cur[tid], re = res[tid];
        for (int p = cu - re; p < cu; ++p)
            packed[p] = resbuf[tid * 16 + (p & 15)];
    }
}

// ---------------- level-2: per-bucket LDS-staged sort -> CSR ----------------
// One 1024-thread block per bucket. Single global read (edges -> registers,
// LDS histogram+rank), scan, scatter into LDS staging, coalesced nt-store out.
__global__ void __launch_bounds__(S2BLK) k_sort2(const int* __restrict__ packed,
                                                 const int* __restrict__ base,
                                                 int* __restrict__ packed2,
                                                 int* __restrict__ rowptr,
                                                 int sbits, int K, int E) {
    __shared__ int cnt[BSIZE];
    __shared__ int sc[BSIZE];
    __shared__ int startsh[BSIZE];
    __shared__ int cur[BSIZE];
    extern __shared__ int sorted[];      // S2CAP ints (72 KB)
    int k = blockIdx.x;
    int tid = threadIdx.x;
    int lo = base[k], hi = base[k + 1];
    int len = hi - lo;
    bool fits = (len <= S2CAP);          // block-uniform

    if (tid < BSIZE) cnt[tid] = 0;
    __syncthreads();

    int v[S2MAXJ], r[S2MAXJ];
    if (fits) {
        // load whole bucket to regs + LDS histogram with rank capture
#pragma unroll
        for (int j = 0; j < S2MAXJ; ++j) {
            int i = lo + j * S2BLK + tid;
            r[j] = -1;
            if (i < hi) {
                v[j] = ntload(packed + i);
                r[j] = atomicAdd(&cnt[((unsigned)v[j]) >> sbits], 1);
            }
        }
    } else {
        // rare fallback: histogram from global
        for (int i = lo + tid; i < hi; i += S2BLK)
            atomicAdd(&cnt[((unsigned)ntload(packed + i)) >> sbits], 1);
    }
    __syncthreads();

    // scan 256 bins (first 256 threads active; all threads hit barriers)
    if (tid < BSIZE) sc[tid] = cnt[tid];
    __syncthreads();
    for (int off = 1; off < BSIZE; off <<= 1) {
        int u = 0;
        if (tid < BSIZE && tid >= off) u = sc[tid - off];
        __syncthreads();
        if (tid < BSIZE) sc[tid] += u;
        __syncthreads();
    }
    if (tid < BSIZE) {
        int st = sc[tid] - cnt[tid];     // exclusive (bucket-local)
        startsh[tid] = st;
        cur[tid] = lo + st;
        rowptr[(k << BSHIFT) + tid] = lo + st;
    }
    if (k == K - 1 && tid == 0) rowptr[K << BSHIFT] = E;
    __syncthreads();

    if (fits) {
        // scatter into LDS staging
#pragma unroll
        for (int j = 0; j < S2MAXJ; ++j) {
            if (r[j] >= 0)
                sorted[startsh[((unsigned)v[j]) >> sbits] + r[j]] = v[j];
        }
        __syncthreads();
        // coalesced linear write-out
        for (int i = tid; i < len; i += S2BLK)
            __builtin_nontemporal_store(sorted[i], packed2 + lo + i);
    } else {
        // rare fallback: direct global scatter (arrival order within bin)
        for (int i = lo + tid; i < hi; i += S2BLK) {
            int val = ntload(packed + i);
            int pos = atomicAdd(&cur[((unsigned)val) >> sbits], 1);
            packed2[pos] = val;
        }
    }
}

// ---------------- fused aggregation: wave-per-node over CSR -----------------

__global__ void __launch_bounds__(BLK) k_agg4(const int* __restrict__ edges,
                                              const int* __restrict__ rowptr,
                                              const float* __restrict__ dinv,
                                              const float2* __restrict__ pin,
                                              const float* __restrict__ b,
                                              const float* __restrict__ W,
                                              float2* __restrict__ pout,
                                              int N, int smask) {
    int wid = threadIdx.x >> 6, lane = threadIdx.x & 63;
    int n = blockIdx.x * 4 + wid;
    if (n >= N) return;
    int e0 = rowptr[n], e1 = rowptr[n + 1];
    float sx = 0.f, sy = 0.f;
    for (int i = e0 + lane; i < e1; i += 64) {
        float2 e = pin[((unsigned)edges[i]) & smask];
        sx += e.x;
        sy += e.y;
    }
    sx = wave_sum63(sx);
    sy = wave_sum63(sy);
    if (lane == 63) {
        float di = dinv[n];
        float2 self = pin[n];
        float ax = sx + self.x, ay = sy + self.y;
        float h0 = fmaxf(fmaf(di, ax, b[0]), 0.f);
        float h1 = fmaxf(fmaf(di, ay, b[1]), 0.f);
        pout[n] = make_float2(di * (h0 * W[0] + h1 * W[2]),
                              di * (h0 * W[1] + h1 * W[3]));
    }
}

__global__ void __launch_bounds__(BLK) k_agg4f(const int* __restrict__ edges,
                                               const int* __restrict__ rowptr,
                                               const float* __restrict__ dinv,
                                               const float2* __restrict__ pin,
                                               const float* __restrict__ b,
                                               const float* __restrict__ Wr,
                                               float* __restrict__ sv,
                                               int N, int smask) {
    int wid = threadIdx.x >> 6, lane = threadIdx.x & 63;
    int n = blockIdx.x * 4 + wid;
    if (n >= N) return;
    int e0 = rowptr[n], e1 = rowptr[n + 1];
    float sx = 0.f, sy = 0.f;
    for (int i = e0 + lane; i < e1; i += 64) {
        float2 e = pin[((unsigned)edges[i]) & smask];
        sx += e.x;
        sy += e.y;
    }
    sx = wave_sum63(sx);
    sy = wave_sum63(sy);
    if (lane == 63) {
        float di = dinv[n];
        float2 self = pin[n];
        float ax = sx + self.x, ay = sy + self.y;
        float h0 = fmaxf(fmaf(di, ax, b[0]), 0.f);
        float h1 = fmaxf(fmaf(di, ay, b[1]), 0.f);
        sv[n] = fmaf(h0, Wr[0], h1 * Wr[1]);
    }
}

// ---------------- node prologue / pooling ----------------

__global__ void k_node1(const int* __restrict__ rowptr, const float* __restrict__ x,
                        const float* __restrict__ W1, float* __restrict__ dinv,
                        float2* __restrict__ p1, int N) {
    int i = blockIdx.x * BLK + threadIdx.x;
    if (i >= N) return;
    int deg = rowptr[i + 1] - rowptr[i];
    float di = rsqrtf((float)deg + 1.0f);
    dinv[i] = di;
    float2 xv = ((const float2*)x)[i];
    float w00 = W1[0], w01 = W1[1], w10 = W1[2], w11 = W1[3];
    p1[i] = make_float2(di * (xv.x * w00 + xv.y * w10),
                        di * (xv.x * w01 + xv.y * w11));
}

__global__ void k_out_init(float* __restrict__ out, const float* __restrict__ br, int G) {
    int i = blockIdx.x * BLK + threadIdx.x;
    if (i < G) out[i] = br[0];
}

__global__ void k_pool(const float* __restrict__ sv, const int* __restrict__ batch,
                       float* __restrict__ out, int N) {
    int i = blockIdx.x * BLK + threadIdx.x;
    bool valid = i < N;
    float s = valid ? sv[i] : 0.f;
    int key = valid ? batch[i] : -1;
    int lane = threadIdx.x & 63;
    for (int off = 1; off < 64; off <<= 1) {
        float s2 = __shfl_down(s, off);
        int k2 = __shfl_down(key, off);
        if (lane + off < 64 && k2 == key) s += s2;
    }
    int kprev = __shfl_up(key, 1);
    if (valid && (lane == 0 || kprev != key)) unsafeAtomicAdd(&out[key], s);
}

// ---------------- launch ----------------

extern "C" void kernel_launch(void* const* d_in, const int* in_sizes, int n_in,
                              void* d_out, int out_size, void* d_ws, size_t ws_size,
                              hipStream_t stream) {
    const float* x    = (const float*)d_in[0];
    const int*   ei   = (const int*)d_in[1];
    const int*   batch= (const int*)d_in[2];
    const float* W1   = (const float*)d_in[3];
    const float* b1   = (const float*)d_in[4];
    const float* W2   = (const float*)d_in[5];
    const float* b2   = (const float*)d_in[6];
    const float* W3   = (const float*)d_in[7];
    const float* b3   = (const float*)d_in[8];
    const float* Wr   = (const float*)d_in[9];
    const float* br   = (const float*)d_in[10];
    float* out = (float*)d_out;

    int N = in_sizes[0] / 2;
    int E = in_sizes[1] / 2;
    int G = out_size;
    const int* src = ei;
    const int* dst = ei + E;

    int K = (N + BSIZE - 1) >> BSHIFT;
    if (K > KPAD) return;                       // shape guard
    int S = NSLICE;
    int chunk = (E + S - 1) / S;

    int sbits = 1;
    while ((1 << sbits) < N) ++sbits;           // 18 for N=200000
    if (sbits + BSHIFT > 31) return;
    int smask = (1 << sbits) - 1;

    auto pad16 = [](size_t b) { return (b + 15) & ~(size_t)15; };
    size_t need = pad16((size_t)E * 4)                 // packed
                + pad16((size_t)S * K * 4)             // hpart
                + pad16((size_t)(K + 1) * 4)           // basep
                + pad16((size_t)K * 4)                 // totals
                + pad16((size_t)E * 4)                 // packed2
                + pad16(((size_t)K * BSIZE + 1) * 4)   // rowptr
                + pad16((size_t)N * 4)                 // dinv
                + 2 * pad16((size_t)N * 8)             // pA, pB
                + pad16((size_t)N * 4);                // sv
    if (need > ws_size) return;

    char* w = (char*)d_ws;
    size_t off = 0;
    auto carve = [&](size_t bytes) { void* p = w + off; off += (bytes + 15) & ~(size_t)15; return p; };
    int*    packed  = (int*)carve((size_t)E * 4);
    int*    hpart   = (int*)carve((size_t)S * K * 4);
    int*    basep   = (int*)carve((size_t)(K + 1) * 4);
    int*    totals  = (int*)carve((size_t)K * 4);
    int*    packed2 = (int*)carve((size_t)E * 4);
    int*    rowptr  = (int*)carve(((size_t)K * BSIZE + 1) * 4);
    float*  dinv    = (float*)carve((size_t)N * 4);
    float2* pA      = (float2*)carve((size_t)N * 8);
    float2* pB      = (float2*)carve((size_t)N * 8);
    float*  sv      = (float*)carve((size_t)N * 4);

    int NB = (N + BLK - 1) / BLK;
    int GB = (G + BLK - 1) / BLK;
    int WB = (N + 3) / 4;                       // wave-per-node grid
    size_t smemK = (size_t)K * 4;

    // level-1: bucket by dst>>8 (256 slices, 1024-thread blocks)
    k_hist   <<<S, BLK2, smemK, stream>>>(dst, hpart, E, chunk, K);
    k_colscan<<<K, NSLICE, 0, stream>>>(hpart, totals, K);
    k_base   <<<1, SCAN_T, 0, stream>>>(totals, basep, K);
    k_scatter<<<S, BLK2, (size_t)K * 16 * 4, stream>>>(src, dst, hpart, basep, packed,
                                                       E, chunk, K, sbits);

    // level-2: LDS-staged per-bucket sort -> CSR (rowptr side-output)
    k_sort2  <<<K, S2BLK, (size_t)S2CAP * 4, stream>>>(packed, basep, packed2, rowptr,
                                                       sbits, K, E);

    // dinv + p1
    k_node1  <<<NB, BLK, 0, stream>>>(rowptr, x, W1, dinv, pA, N);

    // fused layers (agg + relu + next matmul)
    k_agg4   <<<WB, BLK, 0, stream>>>(packed2, rowptr, dinv, pA, b1, W2, pB, N, smask);
    k_agg4   <<<WB, BLK, 0, stream>>>(packed2, rowptr, dinv, pB, b2, W3, pA, N, smask);
    k_agg4f  <<<WB, BLK, 0, stream>>>(packed2, rowptr, dinv, pA, b3, Wr, sv, N, smask);

    // pool + readout
    k_out_init<<<GB, BLK, 0, stream>>>(out, br, G);
    k_pool    <<<NB, BLK, 0, stream>>>(sv, batch, out, N);
}

// Round 20
// 364.130 us; speedup vs baseline: 1.0215x; 1.0215x over previous
//
#include <hip/hip_runtime.h>

#define BLK 256
#define BLK2 1024            // wide blocks for level-1 hist/scatter
#define BSHIFT 8
#define BSIZE 256            // nodes per dst bucket == level-2 bins
#define NSLICE 256           // edge slices for level-1 (long runs -> low write amp)
#define SCAN_T 1024          // k_base scan width (K <= 1024)
#define KPAD 1024            // level-1 bin array size (K <= 1024)
#define EPT 8                // edges per thread per tile
#define TILE2 (BLK2 * EPT)   // level-1 staging tile (8192)
#define S2BLK 1024           // k_sort2 block size
#define S2CAP 18432          // max edges per bucket staged in LDS (72 KB)
#define S2MAXJ 18            // S2CAP / S2BLK

typedef int iv4 __attribute__((ext_vector_type(4)));

template <typename T>
__device__ __forceinline__ T ntload(const T* p) { return __builtin_nontemporal_load(p); }

__device__ __forceinline__ iv4 ntload4(const int* p) {
    return __builtin_nontemporal_load((const iv4*)p);
}

// DPP wave-sum (rocPRIM gfx9 sequence): result lands in lane 63.
template <int CTRL>
__device__ __forceinline__ float dpp_add(float v) {
    int t = __builtin_amdgcn_update_dpp(0, __float_as_int(v), CTRL, 0xf, 0xf, true);
    return v + __int_as_float(t);
}
__device__ __forceinline__ float wave_sum63(float v) {
    v = dpp_add<0x111>(v);   // row_shr:1
    v = dpp_add<0x112>(v);   // row_shr:2
    v = dpp_add<0x114>(v);   // row_shr:4
    v = dpp_add<0x118>(v);   // row_shr:8
    v = dpp_add<0x142>(v);   // row_bcast:15
    v = dpp_add<0x143>(v);   // row_bcast:31 -> lane63 = total
    return v;
}

// ---------------- level-1: bucket by dst>>8 (no global atomics) -------------

__global__ void __launch_bounds__(BLK2) k_hist(const int* __restrict__ dst,
                                               int* __restrict__ partial,
                                               int E, int chunk, int K) {
    extern __shared__ int cnt[];
    int s = blockIdx.x;
    for (int i = threadIdx.x; i < K; i += BLK2) cnt[i] = 0;
    __syncthreads();
    int lo = s * chunk, hi = min(E, lo + chunk);
    int a0 = min((lo + 3) & ~3, hi);
    int a1 = max(hi & ~3, a0);
    for (int i = lo + threadIdx.x; i < a0; i += BLK2)
        atomicAdd(&cnt[((unsigned)ntload(dst + i)) >> BSHIFT], 1);
    for (int i = a0 + 4 * threadIdx.x; i < a1; i += 4 * BLK2) {
        iv4 q = ntload4(dst + i);
        atomicAdd(&cnt[((unsigned)q.x) >> BSHIFT], 1);
        atomicAdd(&cnt[((unsigned)q.y) >> BSHIFT], 1);
        atomicAdd(&cnt[((unsigned)q.z) >> BSHIFT], 1);
        atomicAdd(&cnt[((unsigned)q.w) >> BSHIFT], 1);
    }
    for (int i = a1 + threadIdx.x; i < hi; i += BLK2)
        atomicAdd(&cnt[((unsigned)ntload(dst + i)) >> BSHIFT], 1);
    __syncthreads();
    int* prow = partial + (size_t)s * K;
    for (int i = threadIdx.x; i < K; i += BLK2) prow[i] = cnt[i];
}

__global__ void __launch_bounds__(NSLICE) k_colscan(int* __restrict__ partial,
                                                    int* __restrict__ totals, int K) {
    __shared__ int sh[NSLICE];
    int k = blockIdx.x;
    int t = threadIdx.x;                  // blockDim.x == NSLICE
    int v = partial[(size_t)t * K + k];
    sh[t] = v;
    __syncthreads();
    for (int off = 1; off < NSLICE; off <<= 1) {
        int u = (t >= off) ? sh[t - off] : 0;
        __syncthreads();
        sh[t] += u;
        __syncthreads();
    }
    partial[(size_t)t * K + k] = sh[t] - v;
    if (t == NSLICE - 1) totals[k] = sh[t];
}

__global__ void __launch_bounds__(SCAN_T) k_base(const int* __restrict__ totals,
                                                 int* __restrict__ base, int K) {
    __shared__ int sh[SCAN_T];
    int t = threadIdx.x;
    int v = (t < K) ? totals[t] : 0;
    sh[t] = v;
    __syncthreads();
    for (int off = 1; off < SCAN_T; off <<= 1) {
        int u = (t >= off) ? sh[t - off] : 0;
        __syncthreads();
        sh[t] += u;
        __syncthreads();
    }
    if (t < K) base[t + 1] = sh[t];
    if (t == 0) base[0] = 0;
}

// 1024-thread tile counting-sort scatter: packed = (dst_local << sbits) | src
__global__ void __launch_bounds__(BLK2) k_scatter(const int* __restrict__ src,
                                                  const int* __restrict__ dst,
                                                  const int* __restrict__ offs,
                                                  const int* __restrict__ base,
                                                  int* __restrict__ packed,
                                                  int E, int chunk, int K, int sbits) {
    __shared__ int cnt[KPAD];
    __shared__ int cur[KPAD];
    __shared__ int gstart[KPAD];
    __shared__ int tsum[KPAD];
    __shared__ int sval[TILE2];
    __shared__ int sadr[TILE2];
    int s = blockIdx.x;
    int tid = threadIdx.x;
    const int* orow = offs + (size_t)s * K;
    cur[tid] = (tid < K) ? orow[tid] + base[tid] : 0;
    int lo = s * chunk, hi = min(E, lo + chunk);

    for (int tlo = lo; tlo < hi; tlo += TILE2) {
        cnt[tid] = 0;
        __syncthreads();

        int kk[EPT], rr[EPT], vv[EPT];
#pragma unroll
        for (int j = 0; j < EPT; ++j) {
            int i = tlo + j * BLK2 + tid;
            kk[j] = -1;
            if (i < hi) {
                int d = ntload(dst + i);
                int sc = ntload(src + i);
                kk[j] = ((unsigned)d) >> BSHIFT;
                vv[j] = ((d & (BSIZE - 1)) << sbits) | sc;
                rr[j] = atomicAdd(&cnt[kk[j]], 1);
            }
        }
        __syncthreads();

        // 1024-wide direct bin scan (1 bin/thread)
        int c = cnt[tid];
        tsum[tid] = c;
        __syncthreads();
        for (int off = 1; off < KPAD; off <<= 1) {
            int u = (tid >= off) ? tsum[tid - off] : 0;
            __syncthreads();
            tsum[tid] += u;
            __syncthreads();
        }
        int excl = tsum[tid] - c;
        gstart[tid] = cur[tid];
        cur[tid] += c;
        cnt[tid] = excl;
        __syncthreads();

#pragma unroll
        for (int j = 0; j < EPT; ++j) {
            if (kk[j] >= 0) {
                int idx = cnt[kk[j]] + rr[j];
                sval[idx] = vv[j];
                sadr[idx] = gstart[kk[j]] + rr[j];
            }
        }
        __syncthreads();

        int tot = min(hi - tlo, TILE2);
        for (int i2 = tid; i2 < tot; i2 += BLK2)
            packed[sadr[i2]] = sval[i2];
        __syncthreads();
    }
}

// ---------------- level-2: per-bucket LDS-staged sort -> CSR + node prologue
// One 1024-thread block per bucket. Single global read (edges -> registers,
// LDS histogram+rank), scan, scatter into LDS staging, coalesced nt-store out.
// Epilogue: per-node degree is in cnt[] -> fused dinv + p1 = dinv*(x@W1).
__global__ void __launch_bounds__(S2BLK) k_sort2(const int* __restrict__ packed,
                                                 const int* __restrict__ base,
                                                 int* __restrict__ packed2,
                                                 int* __restrict__ rowptr,
                                                 const float* __restrict__ x,
                                                 const float* __restrict__ W1,
                                                 float* __restrict__ dinv,
                                                 float2* __restrict__ p1,
                                                 int sbits, int K, int E, int N) {
    __shared__ int cnt[BSIZE];
    __shared__ int sc[BSIZE];
    __shared__ int startsh[BSIZE];
    __shared__ int cur[BSIZE];
    extern __shared__ int sorted[];      // S2CAP ints (72 KB)
    int k = blockIdx.x;
    int tid = threadIdx.x;
    int lo = base[k], hi = base[k + 1];
    int len = hi - lo;
    bool fits = (len <= S2CAP);          // block-uniform

    if (tid < BSIZE) cnt[tid] = 0;
    __syncthreads();

    int v[S2MAXJ], r[S2MAXJ];
    if (fits) {
        // load whole bucket to regs + LDS histogram with rank capture
#pragma unroll
        for (int j = 0; j < S2MAXJ; ++j) {
            int i = lo + j * S2BLK + tid;
            r[j] = -1;
            if (i < hi) {
                v[j] = ntload(packed + i);
                r[j] = atomicAdd(&cnt[((unsigned)v[j]) >> sbits], 1);
            }
        }
    } else {
        // rare fallback: histogram from global
        for (int i = lo + tid; i < hi; i += S2BLK)
            atomicAdd(&cnt[((unsigned)ntload(packed + i)) >> sbits], 1);
    }
    __syncthreads();

    // scan 256 bins (first 256 threads active; all threads hit barriers)
    if (tid < BSIZE) sc[tid] = cnt[tid];
    __syncthreads();
    for (int off = 1; off < BSIZE; off <<= 1) {
        int u = 0;
        if (tid < BSIZE && tid >= off) u = sc[tid - off];
        __syncthreads();
        if (tid < BSIZE) sc[tid] += u;
        __syncthreads();
    }
    if (tid < BSIZE) {
        int st = sc[tid] - cnt[tid];     // exclusive (bucket-local)
        startsh[tid] = st;
        cur[tid] = lo + st;
        rowptr[(k << BSHIFT) + tid] = lo + st;
    }
    if (k == K - 1 && tid == 0) rowptr[K << BSHIFT] = E;

    // fused node prologue: degree = cnt[tid] for node k*256+tid
    if (tid < BSIZE) {
        int n = (k << BSHIFT) + tid;
        if (n < N) {
            float di = rsqrtf((float)cnt[tid] + 1.0f);
            dinv[n] = di;
            float2 xv = ((const float2*)x)[n];
            float w00 = W1[0], w01 = W1[1], w10 = W1[2], w11 = W1[3];
            p1[n] = make_float2(di * (xv.x * w00 + xv.y * w10),
                                di * (xv.x * w01 + xv.y * w11));
        }
    }
    __syncthreads();

    if (fits) {
        // scatter into LDS staging
#pragma unroll
        for (int j = 0; j < S2MAXJ; ++j) {
            if (r[j] >= 0)
                sorted[startsh[((unsigned)v[j]) >> sbits] + r[j]] = v[j];
        }
        __syncthreads();
        // coalesced linear write-out
        for (int i = tid; i < len; i += S2BLK)
            __builtin_nontemporal_store(sorted[i], packed2 + lo + i);
    } else {
        // rare fallback: direct global scatter (arrival order within bin)
        for (int i = lo + tid; i < hi; i += S2BLK) {
            int val = ntload(packed + i);
            int pos = atomicAdd(&cur[((unsigned)val) >> sbits], 1);
            packed2[pos] = val;
        }
    }
}

// ---------------- fused aggregation: wave-per-node over CSR -----------------

__global__ void __launch_bounds__(BLK) k_agg4(const int* __restrict__ edges,
                                              const int* __restrict__ rowptr,
                                              const float* __restrict__ dinv,
                                              const float2* __restrict__ pin,
                                              const float* __restrict__ b,
                                              const float* __restrict__ W,
                                              float2* __restrict__ pout,
                                              int N, int smask) {
    int wid = threadIdx.x >> 6, lane = threadIdx.x & 63;
    int n = blockIdx.x * 4 + wid;
    if (n >= N) return;
    int e0 = rowptr[n], e1 = rowptr[n + 1];
    float sx = 0.f, sy = 0.f;
    for (int i = e0 + lane; i < e1; i += 64) {
        float2 e = pin[((unsigned)edges[i]) & smask];
        sx += e.x;
        sy += e.y;
    }
    sx = wave_sum63(sx);
    sy = wave_sum63(sy);
    if (lane == 63) {
        float di = dinv[n];
        float2 self = pin[n];
        float ax = sx + self.x, ay = sy + self.y;
        float h0 = fmaxf(fmaf(di, ax, b[0]), 0.f);
        float h1 = fmaxf(fmaf(di, ay, b[1]), 0.f);
        pout[n] = make_float2(di * (h0 * W[0] + h1 * W[2]),
                              di * (h0 * W[1] + h1 * W[3]));
    }
}

__global__ void __launch_bounds__(BLK) k_agg4f(const int* __restrict__ edges,
                                               const int* __restrict__ rowptr,
                                               const float* __restrict__ dinv,
                                               const float2* __restrict__ pin,
                                               const float* __restrict__ b,
                                               const float* __restrict__ Wr,
                                               float* __restrict__ sv,
                                               int N, int smask) {
    int wid = threadIdx.x >> 6, lane = threadIdx.x & 63;
    int n = blockIdx.x * 4 + wid;
    if (n >= N) return;
    int e0 = rowptr[n], e1 = rowptr[n + 1];
    float sx = 0.f, sy = 0.f;
    for (int i = e0 + lane; i < e1; i += 64) {
        float2 e = pin[((unsigned)edges[i]) & smask];
        sx += e.x;
        sy += e.y;
    }
    sx = wave_sum63(sx);
    sy = wave_sum63(sy);
    if (lane == 63) {
        float di = dinv[n];
        float2 self = pin[n];
        float ax = sx + self.x, ay = sy + self.y;
        float h0 = fmaxf(fmaf(di, ax, b[0]), 0.f);
        float h1 = fmaxf(fmaf(di, ay, b[1]), 0.f);
        sv[n] = fmaf(h0, Wr[0], h1 * Wr[1]);
    }
}

// ---------------- pooling ----------------

__global__ void k_out_init(float* __restrict__ out, const float* __restrict__ br, int G) {
    int i = blockIdx.x * BLK + threadIdx.x;
    if (i < G) out[i] = br[0];
}

__global__ void k_pool(const float* __restrict__ sv, const int* __restrict__ batch,
                       float* __restrict__ out, int N) {
    int i = blockIdx.x * BLK + threadIdx.x;
    bool valid = i < N;
    float s = valid ? sv[i] : 0.f;
    int key = valid ? batch[i] : -1;
    int lane = threadIdx.x & 63;
    for (int off = 1; off < 64; off <<= 1) {
        float s2 = __shfl_down(s, off);
        int k2 = __shfl_down(key, off);
        if (lane + off < 64 && k2 == key) s += s2;
    }
    int kprev = __shfl_up(key, 1);
    if (valid && (lane == 0 || kprev != key)) unsafeAtomicAdd(&out[key], s);
}

// ---------------- launch ----------------

extern "C" void kernel_launch(void* const* d_in, const int* in_sizes, int n_in,
                              void* d_out, int out_size, void* d_ws, size_t ws_size,
                              hipStream_t stream) {
    const float* x    = (const float*)d_in[0];
    const int*   ei   = (const int*)d_in[1];
    const int*   batch= (const int*)d_in[2];
    const float* W1   = (const float*)d_in[3];
    const float* b1   = (const float*)d_in[4];
    const float* W2   = (const float*)d_in[5];
    const float* b2   = (const float*)d_in[6];
    const float* W3   = (const float*)d_in[7];
    const float* b3   = (const float*)d_in[8];
    const float* Wr   = (const float*)d_in[9];
    const float* br   = (const float*)d_in[10];
    float* out = (float*)d_out;

    int N = in_sizes[0] / 2;
    int E = in_sizes[1] / 2;
    int G = out_size;
    const int* src = ei;
    const int* dst = ei + E;

    int K = (N + BSIZE - 1) >> BSHIFT;
    if (K > KPAD) return;                       // shape guard
    int S = NSLICE;
    int chunk = (E + S - 1) / S;

    int sbits = 1;
    while ((1 << sbits) < N) ++sbits;           // 18 for N=200000
    if (sbits + BSHIFT > 31) return;
    int smask = (1 << sbits) - 1;

    auto pad16 = [](size_t b) { return (b + 15) & ~(size_t)15; };
    size_t need = pad16((size_t)E * 4)                 // packed
                + pad16((size_t)S * K * 4)             // hpart
                + pad16((size_t)(K + 1) * 4)           // basep
                + pad16((size_t)K * 4)                 // totals
                + pad16((size_t)E * 4)                 // packed2
                + pad16(((size_t)K * BSIZE + 1) * 4)   // rowptr
                + pad16((size_t)N * 4)                 // dinv
                + 2 * pad16((size_t)N * 8)             // pA, pB
                + pad16((size_t)N * 4);                // sv
    if (need > ws_size) return;

    char* w = (char*)d_ws;
    size_t off = 0;
    auto carve = [&](size_t bytes) { void* p = w + off; off += (bytes + 15) & ~(size_t)15; return p; };
    int*    packed  = (int*)carve((size_t)E * 4);
    int*    hpart   = (int*)carve((size_t)S * K * 4);
    int*    basep   = (int*)carve((size_t)(K + 1) * 4);
    int*    totals  = (int*)carve((size_t)K * 4);
    int*    packed2 = (int*)carve((size_t)E * 4);
    int*    rowptr  = (int*)carve(((size_t)K * BSIZE + 1) * 4);
    float*  dinv    = (float*)carve((size_t)N * 4);
    float2* pA      = (float2*)carve((size_t)N * 8);
    float2* pB      = (float2*)carve((size_t)N * 8);
    float*  sv      = (float*)carve((size_t)N * 4);

    int NB = (N + BLK - 1) / BLK;
    int GB = (G + BLK - 1) / BLK;
    int WB = (N + 3) / 4;                       // wave-per-node grid
    size_t smemK = (size_t)K * 4;

    // level-1: bucket by dst>>8 (256 slices, 1024-thread blocks)
    k_hist   <<<S, BLK2, smemK, stream>>>(dst, hpart, E, chunk, K);
    k_colscan<<<K, NSLICE, 0, stream>>>(hpart, totals, K);
    k_base   <<<1, SCAN_T, 0, stream>>>(totals, basep, K);
    k_scatter<<<S, BLK2, 0, stream>>>(src, dst, hpart, basep, packed, E, chunk, K, sbits);

    // level-2: LDS-staged per-bucket sort -> CSR + fused dinv/p1 prologue
    k_sort2  <<<K, S2BLK, (size_t)S2CAP * 4, stream>>>(packed, basep, packed2, rowptr,
                                                       x, W1, dinv, pA, sbits, K, E, N);

    // fused layers (agg + relu + next matmul)
    k_agg4   <<<WB, BLK, 0, stream>>>(packed2, rowptr, dinv, pA, b1, W2, pB, N, smask);
    k_agg4   <<<WB, BLK, 0, stream>>>(packed2, rowptr, dinv, pB, b2, W3, pA, N, smask);
    k_agg4f  <<<WB, BLK, 0, stream>>>(packed2, rowptr, dinv, pA, b3, Wr, sv, N, smask);

    // pool + readout
    k_out_init<<<GB, BLK, 0, stream>>>(out, br, G);
    k_pool    <<<NB, BLK, 0, stream>>>(sv, batch, out, N);
}

// Round 21
// 352.628 us; speedup vs baseline: 1.0548x; 1.0326x over previous
//
#include <hip/hip_runtime.h>

#define BLK 256
#define BLK2 1024            // wide blocks for level-1 hist/scatter
#define BSHIFT 8
#define BSIZE 256            // nodes per dst bucket == level-2 bins
#define NSLICE 256           // edge slices for level-1 (long runs -> low write amp)
#define SCAN_T 1024          // k_base scan width (K <= 1024)
#define KPAD 1024            // level-1 bin array size (K <= 1024)
#define EPT 8                // edges per thread (hist vector loop granularity)
#define EPT2 16              // edges per thread per scatter tile
#define TILE2 (BLK2 * EPT2)  // level-1 staging tile (16384): lines fill in-tile
#define S2BLK 1024           // k_sort2 block size
#define S2CAP 18432          // max edges per bucket staged in LDS (72 KB)
#define S2MAXJ 18            // S2CAP / S2BLK

typedef int iv4 __attribute__((ext_vector_type(4)));

template <typename T>
__device__ __forceinline__ T ntload(const T* p) { return __builtin_nontemporal_load(p); }

__device__ __forceinline__ iv4 ntload4(const int* p) {
    return __builtin_nontemporal_load((const iv4*)p);
}

// DPP wave-sum (rocPRIM gfx9 sequence): result lands in lane 63.
template <int CTRL>
__device__ __forceinline__ float dpp_add(float v) {
    int t = __builtin_amdgcn_update_dpp(0, __float_as_int(v), CTRL, 0xf, 0xf, true);
    return v + __int_as_float(t);
}
__device__ __forceinline__ float wave_sum63(float v) {
    v = dpp_add<0x111>(v);   // row_shr:1
    v = dpp_add<0x112>(v);   // row_shr:2
    v = dpp_add<0x114>(v);   // row_shr:4
    v = dpp_add<0x118>(v);   // row_shr:8
    v = dpp_add<0x142>(v);   // row_bcast:15
    v = dpp_add<0x143>(v);   // row_bcast:31 -> lane63 = total
    return v;
}

// ---------------- level-1: bucket by dst>>8 (no global atomics) -------------

__global__ void __launch_bounds__(BLK2) k_hist(const int* __restrict__ dst,
                                               int* __restrict__ partial,
                                               int E, int chunk, int K) {
    extern __shared__ int cnt[];
    int s = blockIdx.x;
    for (int i = threadIdx.x; i < K; i += BLK2) cnt[i] = 0;
    __syncthreads();
    int lo = s * chunk, hi = min(E, lo + chunk);
    int a0 = min((lo + 3) & ~3, hi);
    int a1 = max(hi & ~3, a0);
    for (int i = lo + threadIdx.x; i < a0; i += BLK2)
        atomicAdd(&cnt[((unsigned)ntload(dst + i)) >> BSHIFT], 1);
    for (int i = a0 + 4 * threadIdx.x; i < a1; i += 4 * BLK2) {
        iv4 q = ntload4(dst + i);
        atomicAdd(&cnt[((unsigned)q.x) >> BSHIFT], 1);
        atomicAdd(&cnt[((unsigned)q.y) >> BSHIFT], 1);
        atomicAdd(&cnt[((unsigned)q.z) >> BSHIFT], 1);
        atomicAdd(&cnt[((unsigned)q.w) >> BSHIFT], 1);
    }
    for (int i = a1 + threadIdx.x; i < hi; i += BLK2)
        atomicAdd(&cnt[((unsigned)ntload(dst + i)) >> BSHIFT], 1);
    __syncthreads();
    int* prow = partial + (size_t)s * K;
    for (int i = threadIdx.x; i < K; i += BLK2) prow[i] = cnt[i];
}

__global__ void __launch_bounds__(NSLICE) k_colscan(int* __restrict__ partial,
                                                    int* __restrict__ totals, int K) {
    __shared__ int sh[NSLICE];
    int k = blockIdx.x;
    int t = threadIdx.x;                  // blockDim.x == NSLICE
    int v = partial[(size_t)t * K + k];
    sh[t] = v;
    __syncthreads();
    for (int off = 1; off < NSLICE; off <<= 1) {
        int u = (t >= off) ? sh[t - off] : 0;
        __syncthreads();
        sh[t] += u;
        __syncthreads();
    }
    partial[(size_t)t * K + k] = sh[t] - v;
    if (t == NSLICE - 1) totals[k] = sh[t];
}

__global__ void __launch_bounds__(SCAN_T) k_base(const int* __restrict__ totals,
                                                 int* __restrict__ base, int K) {
    __shared__ int sh[SCAN_T];
    int t = threadIdx.x;
    int v = (t < K) ? totals[t] : 0;
    sh[t] = v;
    __syncthreads();
    for (int off = 1; off < SCAN_T; off <<= 1) {
        int u = (t >= off) ? sh[t - off] : 0;
        __syncthreads();
        sh[t] += u;
        __syncthreads();
    }
    if (t < K) base[t + 1] = sh[t];
    if (t == 0) base[0] = 0;
}

// 1024-thread tile counting-sort scatter, 16K-edge staging tile:
// packed = (dst_local << sbits) | src
__global__ void __launch_bounds__(BLK2) k_scatter(const int* __restrict__ src,
                                                  const int* __restrict__ dst,
                                                  const int* __restrict__ offs,
                                                  const int* __restrict__ base,
                                                  int* __restrict__ packed,
                                                  int E, int chunk, int K, int sbits) {
    __shared__ int cnt[KPAD];
    __shared__ int cur[KPAD];
    __shared__ int gstart[KPAD];
    __shared__ int tsum[KPAD];
    extern __shared__ int smem[];         // sval[TILE2] + sadr[TILE2] (128 KB)
    int* sval = smem;
    int* sadr = smem + TILE2;
    int s = blockIdx.x;
    int tid = threadIdx.x;
    const int* orow = offs + (size_t)s * K;
    cur[tid] = (tid < K) ? orow[tid] + base[tid] : 0;
    int lo = s * chunk, hi = min(E, lo + chunk);

    for (int tlo = lo; tlo < hi; tlo += TILE2) {
        cnt[tid] = 0;
        __syncthreads();

        int kk[EPT2], rr[EPT2], vv[EPT2];
#pragma unroll
        for (int j = 0; j < EPT2; ++j) {
            int i = tlo + j * BLK2 + tid;
            kk[j] = -1;
            if (i < hi) {
                int d = ntload(dst + i);
                int sc = ntload(src + i);
                kk[j] = ((unsigned)d) >> BSHIFT;
                vv[j] = ((d & (BSIZE - 1)) << sbits) | sc;
                rr[j] = atomicAdd(&cnt[kk[j]], 1);
            }
        }
        __syncthreads();

        // 1024-wide direct bin scan (1 bin/thread)
        int c = cnt[tid];
        tsum[tid] = c;
        __syncthreads();
        for (int off = 1; off < KPAD; off <<= 1) {
            int u = (tid >= off) ? tsum[tid - off] : 0;
            __syncthreads();
            tsum[tid] += u;
            __syncthreads();
        }
        int excl = tsum[tid] - c;
        gstart[tid] = cur[tid];
        cur[tid] += c;
        cnt[tid] = excl;
        __syncthreads();

#pragma unroll
        for (int j = 0; j < EPT2; ++j) {
            if (kk[j] >= 0) {
                int idx = cnt[kk[j]] + rr[j];
                sval[idx] = vv[j];
                sadr[idx] = gstart[kk[j]] + rr[j];
            }
        }
        __syncthreads();

        int tot = min(hi - tlo, TILE2);
        for (int i2 = tid; i2 < tot; i2 += BLK2)
            packed[sadr[i2]] = sval[i2];
        __syncthreads();
    }
}

// ---------------- level-2: per-bucket LDS-staged sort -> CSR + node prologue
__global__ void __launch_bounds__(S2BLK) k_sort2(const int* __restrict__ packed,
                                                 const int* __restrict__ base,
                                                 int* __restrict__ packed2,
                                                 int* __restrict__ rowptr,
                                                 const float* __restrict__ x,
                                                 const float* __restrict__ W1,
                                                 float* __restrict__ dinv,
                                                 float2* __restrict__ p1,
                                                 int sbits, int K, int E, int N) {
    __shared__ int cnt[BSIZE];
    __shared__ int sc[BSIZE];
    __shared__ int startsh[BSIZE];
    __shared__ int cur[BSIZE];
    extern __shared__ int sorted[];      // S2CAP ints (72 KB)
    int k = blockIdx.x;
    int tid = threadIdx.x;
    int lo = base[k], hi = base[k + 1];
    int len = hi - lo;
    bool fits = (len <= S2CAP);          // block-uniform

    if (tid < BSIZE) cnt[tid] = 0;
    __syncthreads();

    int v[S2MAXJ], r[S2MAXJ];
    if (fits) {
#pragma unroll
        for (int j = 0; j < S2MAXJ; ++j) {
            int i = lo + j * S2BLK + tid;
            r[j] = -1;
            if (i < hi) {
                v[j] = ntload(packed + i);
                r[j] = atomicAdd(&cnt[((unsigned)v[j]) >> sbits], 1);
            }
        }
    } else {
        for (int i = lo + tid; i < hi; i += S2BLK)
            atomicAdd(&cnt[((unsigned)ntload(packed + i)) >> sbits], 1);
    }
    __syncthreads();

    if (tid < BSIZE) sc[tid] = cnt[tid];
    __syncthreads();
    for (int off = 1; off < BSIZE; off <<= 1) {
        int u = 0;
        if (tid < BSIZE && tid >= off) u = sc[tid - off];
        __syncthreads();
        if (tid < BSIZE) sc[tid] += u;
        __syncthreads();
    }
    if (tid < BSIZE) {
        int st = sc[tid] - cnt[tid];     // exclusive (bucket-local)
        startsh[tid] = st;
        cur[tid] = lo + st;
        rowptr[(k << BSHIFT) + tid] = lo + st;
    }
    if (k == K - 1 && tid == 0) rowptr[K << BSHIFT] = E;

    // fused node prologue: degree = cnt[tid] for node k*256+tid
    if (tid < BSIZE) {
        int n = (k << BSHIFT) + tid;
        if (n < N) {
            float di = rsqrtf((float)cnt[tid] + 1.0f);
            dinv[n] = di;
            float2 xv = ((const float2*)x)[n];
            float w00 = W1[0], w01 = W1[1], w10 = W1[2], w11 = W1[3];
            p1[n] = make_float2(di * (xv.x * w00 + xv.y * w10),
                                di * (xv.x * w01 + xv.y * w11));
        }
    }
    __syncthreads();

    if (fits) {
#pragma unroll
        for (int j = 0; j < S2MAXJ; ++j) {
            if (r[j] >= 0)
                sorted[startsh[((unsigned)v[j]) >> sbits] + r[j]] = v[j];
        }
        __syncthreads();
        for (int i = tid; i < len; i += S2BLK)
            __builtin_nontemporal_store(sorted[i], packed2 + lo + i);
    } else {
        for (int i = lo + tid; i < hi; i += S2BLK) {
            int val = ntload(packed + i);
            int pos = atomicAdd(&cur[((unsigned)val) >> sbits], 1);
            packed2[pos] = val;
        }
    }
}

// ---------------- fused aggregation: wave-per-node over CSR -----------------

__global__ void __launch_bounds__(BLK) k_agg4(const int* __restrict__ edges,
                                              const int* __restrict__ rowptr,
                                              const float* __restrict__ dinv,
                                              const float2* __restrict__ pin,
                                              const float* __restrict__ b,
                                              const float* __restrict__ W,
                                              float2* __restrict__ pout,
                                              int N, int smask) {
    int wid = threadIdx.x >> 6, lane = threadIdx.x & 63;
    int n = blockIdx.x * 4 + wid;
    if (n >= N) return;
    int e0 = rowptr[n], e1 = rowptr[n + 1];
    float sx = 0.f, sy = 0.f;
    for (int i = e0 + lane; i < e1; i += 64) {
        float2 e = pin[((unsigned)edges[i]) & smask];
        sx += e.x;
        sy += e.y;
    }
    sx = wave_sum63(sx);
    sy = wave_sum63(sy);
    if (lane == 63) {
        float di = dinv[n];
        float2 self = pin[n];
        float ax = sx + self.x, ay = sy + self.y;
        float h0 = fmaxf(fmaf(di, ax, b[0]), 0.f);
        float h1 = fmaxf(fmaf(di, ay, b[1]), 0.f);
        pout[n] = make_float2(di * (h0 * W[0] + h1 * W[2]),
                              di * (h0 * W[1] + h1 * W[3]));
    }
}

__global__ void __launch_bounds__(BLK) k_agg4f(const int* __restrict__ edges,
                                               const int* __restrict__ rowptr,
                                               const float* __restrict__ dinv,
                                               const float2* __restrict__ pin,
                                               const float* __restrict__ b,
                                               const float* __restrict__ Wr,
                                               float* __restrict__ sv,
                                               int N, int smask) {
    int wid = threadIdx.x >> 6, lane = threadIdx.x & 63;
    int n = blockIdx.x * 4 + wid;
    if (n >= N) return;
    int e0 = rowptr[n], e1 = rowptr[n + 1];
    float sx = 0.f, sy = 0.f;
    for (int i = e0 + lane; i < e1; i += 64) {
        float2 e = pin[((unsigned)edges[i]) & smask];
        sx += e.x;
        sy += e.y;
    }
    sx = wave_sum63(sx);
    sy = wave_sum63(sy);
    if (lane == 63) {
        float di = dinv[n];
        float2 self = pin[n];
        float ax = sx + self.x, ay = sy + self.y;
        float h0 = fmaxf(fmaf(di, ax, b[0]), 0.f);
        float h1 = fmaxf(fmaf(di, ay, b[1]), 0.f);
        sv[n] = fmaf(h0, Wr[0], h1 * Wr[1]);
    }
}

// ---------------- pooling ----------------

__global__ void k_out_init(float* __restrict__ out, const float* __restrict__ br, int G) {
    int i = blockIdx.x * BLK + threadIdx.x;
    if (i < G) out[i] = br[0];
}

__global__ void k_pool(const float* __restrict__ sv, const int* __restrict__ batch,
                       float* __restrict__ out, int N) {
    int i = blockIdx.x * BLK + threadIdx.x;
    bool valid = i < N;
    float s = valid ? sv[i] : 0.f;
    int key = valid ? batch[i] : -1;
    int lane = threadIdx.x & 63;
    for (int off = 1; off < 64; off <<= 1) {
        float s2 = __shfl_down(s, off);
        int k2 = __shfl_down(key, off);
        if (lane + off < 64 && k2 == key) s += s2;
    }
    int kprev = __shfl_up(key, 1);
    if (valid && (lane == 0 || kprev != key)) unsafeAtomicAdd(&out[key], s);
}

// ---------------- launch ----------------

extern "C" void kernel_launch(void* const* d_in, const int* in_sizes, int n_in,
                              void* d_out, int out_size, void* d_ws, size_t ws_size,
                              hipStream_t stream) {
    const float* x    = (const float*)d_in[0];
    const int*   ei   = (const int*)d_in[1];
    const int*   batch= (const int*)d_in[2];
    const float* W1   = (const float*)d_in[3];
    const float* b1   = (const float*)d_in[4];
    const float* W2   = (const float*)d_in[5];
    const float* b2   = (const float*)d_in[6];
    const float* W3   = (const float*)d_in[7];
    const float* b3   = (const float*)d_in[8];
    const float* Wr   = (const float*)d_in[9];
    const float* br   = (const float*)d_in[10];
    float* out = (float*)d_out;

    int N = in_sizes[0] / 2;
    int E = in_sizes[1] / 2;
    int G = out_size;
    const int* src = ei;
    const int* dst = ei + E;

    int K = (N + BSIZE - 1) >> BSHIFT;
    if (K > KPAD) return;                       // shape guard
    int S = NSLICE;
    int chunk = (E + S - 1) / S;

    int sbits = 1;
    while ((1 << sbits) < N) ++sbits;           // 18 for N=200000
    if (sbits + BSHIFT > 31) return;
    int smask = (1 << sbits) - 1;

    auto pad16 = [](size_t b) { return (b + 15) & ~(size_t)15; };
    size_t need = pad16((size_t)E * 4)                 // packed
                + pad16((size_t)S * K * 4)             // hpart
                + pad16((size_t)(K + 1) * 4)           // basep
                + pad16((size_t)K * 4)                 // totals
                + pad16((size_t)E * 4)                 // packed2
                + pad16(((size_t)K * BSIZE + 1) * 4)   // rowptr
                + pad16((size_t)N * 4)                 // dinv
                + 2 * pad16((size_t)N * 8)             // pA, pB
                + pad16((size_t)N * 4);                // sv
    if (need > ws_size) return;

    char* w = (char*)d_ws;
    size_t off = 0;
    auto carve = [&](size_t bytes) { void* p = w + off; off += (bytes + 15) & ~(size_t)15; return p; };
    int*    packed  = (int*)carve((size_t)E * 4);
    int*    hpart   = (int*)carve((size_t)S * K * 4);
    int*    basep   = (int*)carve((size_t)(K + 1) * 4);
    int*    totals  = (int*)carve((size_t)K * 4);
    int*    packed2 = (int*)carve((size_t)E * 4);
    int*    rowptr  = (int*)carve(((size_t)K * BSIZE + 1) * 4);
    float*  dinv    = (float*)carve((size_t)N * 4);
    float2* pA      = (float2*)carve((size_t)N * 8);
    float2* pB      = (float2*)carve((size_t)N * 8);
    float*  sv      = (float*)carve((size_t)N * 4);

    int NB = (N + BLK - 1) / BLK;
    int GB = (G + BLK - 1) / BLK;
    int WB = (N + 3) / 4;                       // wave-per-node grid
    size_t smemK = (size_t)K * 4;

    // level-1: bucket by dst>>8 (256 slices, 1024-thread blocks, 16K tiles)
    k_hist   <<<S, BLK2, smemK, stream>>>(dst, hpart, E, chunk, K);
    k_colscan<<<K, NSLICE, 0, stream>>>(hpart, totals, K);
    k_base   <<<1, SCAN_T, 0, stream>>>(totals, basep, K);
    k_scatter<<<S, BLK2, (size_t)TILE2 * 2 * 4, stream>>>(src, dst, hpart, basep, packed,
                                                          E, chunk, K, sbits);

    // level-2: LDS-staged per-bucket sort -> CSR + fused dinv/p1 prologue
    k_sort2  <<<K, S2BLK, (size_t)S2CAP * 4, stream>>>(packed, basep, packed2, rowptr,
                                                       x, W1, dinv, pA, sbits, K, E, N);

    // fused layers (agg + relu + next matmul)
    k_agg4   <<<WB, BLK, 0, stream>>>(packed2, rowptr, dinv, pA, b1, W2, pB, N, smask);
    k_agg4   <<<WB, BLK, 0, stream>>>(packed2, rowptr, dinv, pB, b2, W3, pA, N, smask);
    k_agg4f  <<<WB, BLK, 0, stream>>>(packed2, rowptr, dinv, pA, b3, Wr, sv, N, smask);

    // pool + readout
    k_out_init<<<GB, BLK, 0, stream>>>(out, br, G);
    k_pool    <<<NB, BLK, 0, stream>>>(sv, batch, out, N);
}